// Round 1
// baseline (553.726 us; speedup 1.0000x reference)
//
#include <hip/hip_runtime.h>
#include <math.h>

#define N_NODES 8192
#define IN_DIM  512
#define OUT_DIM 512
#define KN      16

// ---------------- projection GEMM: C = A @ W^T ----------------
// A [M,K] row-major, W [N,K] row-major, C [M,N] = A * W^T
#define BM 128
#define BN 128
#define BKK 32

__global__ __launch_bounds__(256) void proj_gemm(
    const float* __restrict__ A,
    const float* __restrict__ Bq, const float* __restrict__ Bk, const float* __restrict__ Bv,
    float* __restrict__ Cq, float* __restrict__ Ck, float* __restrict__ Cv) {
  const float* W; float* C;
  if (blockIdx.z == 0)      { W = Bq; C = Cq; }
  else if (blockIdx.z == 1) { W = Bk; C = Ck; }
  else                      { W = Bv; C = Cv; }

  __shared__ float As[BKK][BM];   // k-major so inner reads are float4
  __shared__ float Bs[BKK][BN];

  const int tid  = threadIdx.x;
  const int brow = blockIdx.y * BM;
  const int bcol = blockIdx.x * BN;
  const int tm = (tid >> 4) * 8;   // 16 row-groups * 8 = 128
  const int tn = (tid & 15) * 8;

  float acc[8][8];
  #pragma unroll
  for (int i = 0; i < 8; ++i)
    #pragma unroll
    for (int j = 0; j < 8; ++j) acc[i][j] = 0.f;

  for (int k0 = 0; k0 < IN_DIM; k0 += BKK) {
    #pragma unroll
    for (int l = 0; l < 4; ++l) {
      int lin = tid + l * 256;          // 0..1023  (128 rows * 8 float4/row)
      int r = lin >> 3;                 // 0..127
      int c = (lin & 7) << 2;           // 0,4,...,28
      float4 av = *(const float4*)&A[(size_t)(brow + r) * IN_DIM + k0 + c];
      float4 bv = *(const float4*)&W[(size_t)(bcol + r) * IN_DIM + k0 + c];
      As[c + 0][r] = av.x; As[c + 1][r] = av.y; As[c + 2][r] = av.z; As[c + 3][r] = av.w;
      Bs[c + 0][r] = bv.x; Bs[c + 1][r] = bv.y; Bs[c + 2][r] = bv.z; Bs[c + 3][r] = bv.w;
    }
    __syncthreads();
    #pragma unroll
    for (int kk = 0; kk < BKK; ++kk) {
      float a[8], b[8];
      *(float4*)&a[0] = *(const float4*)&As[kk][tm];
      *(float4*)&a[4] = *(const float4*)&As[kk][tm + 4];
      *(float4*)&b[0] = *(const float4*)&Bs[kk][tn];
      *(float4*)&b[4] = *(const float4*)&Bs[kk][tn + 4];
      #pragma unroll
      for (int i = 0; i < 8; ++i)
        #pragma unroll
        for (int j = 0; j < 8; ++j) acc[i][j] = fmaf(a[i], b[j], acc[i][j]);
    }
    __syncthreads();
  }
  #pragma unroll
  for (int i = 0; i < 8; ++i) {
    float4 v0 = {acc[i][0], acc[i][1], acc[i][2], acc[i][3]};
    float4 v1 = {acc[i][4], acc[i][5], acc[i][6], acc[i][7]};
    size_t off = (size_t)(brow + tm + i) * OUT_DIM + bcol + tn;
    *(float4*)&C[off]     = v0;
    *(float4*)&C[off + 4] = v1;
  }
}

// ---------------- coords: G = h @ Wg^T in float64 (exact ranking basis) ----
__global__ __launch_bounds__(256) void coords_kernel(
    const float* __restrict__ h, const float* __restrict__ Wg,
    double* __restrict__ Gx, double* __restrict__ Gy,
    double* __restrict__ Gz, double* __restrict__ Gsq) {
  int node = (blockIdx.x * blockDim.x + threadIdx.x) >> 6;
  int lane = threadIdx.x & 63;
  if (node >= N_NODES) return;
  const float* hr = h + (size_t)node * IN_DIM;
  double s0 = 0.0, s1 = 0.0, s2 = 0.0;
  for (int k = lane; k < IN_DIM; k += 64) {
    double hv = (double)hr[k];
    s0 += hv * (double)Wg[0 * IN_DIM + k];
    s1 += hv * (double)Wg[1 * IN_DIM + k];
    s2 += hv * (double)Wg[2 * IN_DIM + k];
  }
  #pragma unroll
  for (int off = 32; off; off >>= 1) {
    s0 += __shfl_down(s0, off);
    s1 += __shfl_down(s1, off);
    s2 += __shfl_down(s2, off);
  }
  if (lane == 0) {
    Gx[node] = s0; Gy[node] = s1; Gz[node] = s2;
    Gsq[node] = s0 * s0 + s1 * s1 + s2 * s2;
  }
}

// ---------------- knn: one wave per query, f64 ranking ----------------
// rank by neg_d2 = 2*dot - sq_i - sq_j, descending (largest = nearest)
__global__ __launch_bounds__(256) void knn_kernel(
    const double* __restrict__ Gx, const double* __restrict__ Gy,
    const double* __restrict__ Gz, const double* __restrict__ Gsq,
    int* __restrict__ knn) {
  int q    = (blockIdx.x * blockDim.x + threadIdx.x) >> 6;
  int lane = threadIdx.x & 63;
  if (q >= N_NODES) return;
  const double xi = Gx[q], yi = Gy[q], zi = Gz[q], sqi = Gsq[q];

  double best[KN];
  int    bidx[KN];
  #pragma unroll
  for (int t = 0; t < KN; ++t) { best[t] = -__builtin_inf(); bidx[t] = -1; }

  for (int j = lane; j < N_NODES; j += 64) {
    double dot = xi * Gx[j] + yi * Gy[j] + zi * Gz[j];
    double neg = 2.0 * dot - sqi - Gsq[j];
    if (neg > best[KN - 1]) {
      // fully unrolled insertion (compile-time indices only -> stays in VGPRs)
      #pragma unroll
      for (int t = KN - 1; t >= 1; --t) {
        double bp = best[t - 1]; int ip = bidx[t - 1];
        if (bp < neg) { best[t] = bp; bidx[t] = ip; }
        else if (best[t] < neg) { best[t] = neg; bidx[t] = j; }
      }
      if (best[0] < neg) { best[0] = neg; bidx[0] = j; }
    }
  }

  // merge 64 per-lane sorted lists: 16 rounds of wave argmax over the heads
  for (int t = 0; t < KN; ++t) {
    double bv = best[0];
    int    bl = lane;
    #pragma unroll
    for (int off = 32; off; off >>= 1) {
      double ov = __shfl_xor(bv, off);
      int    ol = __shfl_xor(bl, off);
      if (ov > bv || (ov == bv && ol < bl)) { bv = ov; bl = ol; }
    }
    int wsel = __shfl(bidx[0], bl);
    if (lane == 0) knn[q * KN + t] = wsel;
    if (lane == bl) {
      #pragma unroll
      for (int u = 0; u < KN - 1; ++u) { best[u] = best[u + 1]; bidx[u] = bidx[u + 1]; }
      best[KN - 1] = -__builtin_inf();
    }
  }
}

// ---------------- attend: per dst node, 16 neighbors ----------------
__global__ __launch_bounds__(256) void attend_kernel(
    const float* __restrict__ Q, const float* __restrict__ Km, const float* __restrict__ V,
    const double* __restrict__ Gx, const double* __restrict__ Gy, const double* __restrict__ Gz,
    const int* __restrict__ knn, float* __restrict__ out) {
  const int i    = blockIdx.x;
  const int tid  = threadIdx.x;
  const int wv   = tid >> 6;
  const int lane = tid & 63;

  __shared__ int   s_idx[KN];
  __shared__ float s_w[KN];   // score_e * distance
  __shared__ float s_se[KN];  // score_e

  if (tid < KN) s_idx[tid] = knn[i * KN + tid];
  __syncthreads();

  const float* qr = Q + (size_t)i * OUT_DIM;
  float partial[4];
  #pragma unroll
  for (int s = 0; s < 4; ++s) {
    int src = s_idx[wv * 4 + s];
    const float* kr = Km + (size_t)src * OUT_DIM;
    float acc = 0.f;
    for (int d = lane; d < OUT_DIM; d += 64) acc = fmaf(kr[d], qr[d], acc);
    partial[s] = acc;
  }
  #pragma unroll
  for (int s = 0; s < 4; ++s)
    #pragma unroll
    for (int off = 32; off; off >>= 1) partial[s] += __shfl_down(partial[s], off);

  if (lane == 0) {
    const double xi = Gx[i], yi = Gy[i], zi = Gz[i];
    #pragma unroll
    for (int s = 0; s < 4; ++s) {
      int e = wv * 4 + s;
      int src = s_idx[e];
      float sc = partial[s] / 22.627417f;
      sc = fminf(fmaxf(sc, -5.f), 5.f);
      float se = expf(sc);
      double dx = Gx[src] - xi, dy = Gy[src] - yi, dz = Gz[src] - zi;
      double dd = -sqrt(dx * dx + dy * dy + dz * dz + 1e-6);
      double dc = fmin(fmax(dd / 22.627416997969522, -5.0), 5.0);
      float de = (float)exp(dc);
      s_se[e] = se;
      s_w[e]  = se * de;
    }
  }
  __syncthreads();

  float z = 0.f;
  #pragma unroll
  for (int e = 0; e < KN; ++e) z += s_se[e];

  for (int d = tid; d < OUT_DIM; d += 256) {
    float acc = 0.f;
    #pragma unroll
    for (int e = 0; e < KN; ++e)
      acc = fmaf(s_w[e], V[(size_t)s_idx[e] * OUT_DIM + d], acc);
    out[(size_t)i * OUT_DIM + d] = (z > 0.f) ? (acc / z) : acc;
  }
}

extern "C" void kernel_launch(void* const* d_in, const int* in_sizes, int n_in,
                              void* d_out, int out_size, void* d_ws, size_t ws_size,
                              hipStream_t stream) {
  const float* h  = (const float*)d_in[0];
  const float* Wq = (const float*)d_in[1];
  const float* Wk = (const float*)d_in[2];
  const float* Wv = (const float*)d_in[3];
  const float* Wg = (const float*)d_in[4];
  float* out = (float*)d_out;

  char* ws = (char*)d_ws;
  float* Q = (float*)ws;
  float* K = Q + (size_t)N_NODES * OUT_DIM;
  float* V = K + (size_t)N_NODES * OUT_DIM;
  double* Gx  = (double*)(V + (size_t)N_NODES * OUT_DIM);
  double* Gy  = Gx + N_NODES;
  double* Gz  = Gy + N_NODES;
  double* Gsq = Gz + N_NODES;
  int* knn = (int*)(Gsq + N_NODES);

  dim3 gemm_grid(OUT_DIM / BN, N_NODES / BM, 3);
  hipLaunchKernelGGL(proj_gemm, gemm_grid, dim3(256), 0, stream,
                     h, Wq, Wk, Wv, Q, K, V);
  hipLaunchKernelGGL(coords_kernel, dim3(N_NODES / 4), dim3(256), 0, stream,
                     h, Wg, Gx, Gy, Gz, Gsq);
  hipLaunchKernelGGL(knn_kernel, dim3(N_NODES / 4), dim3(256), 0, stream,
                     Gx, Gy, Gz, Gsq, knn);
  hipLaunchKernelGGL(attend_kernel, dim3(N_NODES), dim3(256), 0, stream,
                     Q, K, V, Gx, Gy, Gz, knn, out);
}

// Round 2
// 316.696 us; speedup vs baseline: 1.7484x; 1.7484x over previous
//
#include <hip/hip_runtime.h>
#include <math.h>

#define N_NODES 8192
#define IN_DIM  512
#define OUT_DIM 512
#define KN      16
#define CAP     128

// ---------------- projection GEMM: C = A @ W^T ----------------
#define BM 128
#define BN 128
#define BKK 32

__global__ __launch_bounds__(256) void proj_gemm(
    const float* __restrict__ A,
    const float* __restrict__ Bq, const float* __restrict__ Bk, const float* __restrict__ Bv,
    float* __restrict__ Cq, float* __restrict__ Ck, float* __restrict__ Cv) {
  const float* W; float* C;
  if (blockIdx.z == 0)      { W = Bq; C = Cq; }
  else if (blockIdx.z == 1) { W = Bk; C = Ck; }
  else                      { W = Bv; C = Cv; }

  __shared__ float As[BKK][BM];
  __shared__ float Bs[BKK][BN];

  const int tid  = threadIdx.x;
  const int brow = blockIdx.y * BM;
  const int bcol = blockIdx.x * BN;
  const int tm = (tid >> 4) * 8;
  const int tn = (tid & 15) * 8;

  float acc[8][8];
  #pragma unroll
  for (int i = 0; i < 8; ++i)
    #pragma unroll
    for (int j = 0; j < 8; ++j) acc[i][j] = 0.f;

  for (int k0 = 0; k0 < IN_DIM; k0 += BKK) {
    #pragma unroll
    for (int l = 0; l < 4; ++l) {
      int lin = tid + l * 256;
      int r = lin >> 3;
      int c = (lin & 7) << 2;
      float4 av = *(const float4*)&A[(size_t)(brow + r) * IN_DIM + k0 + c];
      float4 bv = *(const float4*)&W[(size_t)(bcol + r) * IN_DIM + k0 + c];
      As[c + 0][r] = av.x; As[c + 1][r] = av.y; As[c + 2][r] = av.z; As[c + 3][r] = av.w;
      Bs[c + 0][r] = bv.x; Bs[c + 1][r] = bv.y; Bs[c + 2][r] = bv.z; Bs[c + 3][r] = bv.w;
    }
    __syncthreads();
    #pragma unroll
    for (int kk = 0; kk < BKK; ++kk) {
      float a[8], b[8];
      *(float4*)&a[0] = *(const float4*)&As[kk][tm];
      *(float4*)&a[4] = *(const float4*)&As[kk][tm + 4];
      *(float4*)&b[0] = *(const float4*)&Bs[kk][tn];
      *(float4*)&b[4] = *(const float4*)&Bs[kk][tn + 4];
      #pragma unroll
      for (int i = 0; i < 8; ++i)
        #pragma unroll
        for (int j = 0; j < 8; ++j) acc[i][j] = fmaf(a[i], b[j], acc[i][j]);
    }
    __syncthreads();
  }
  #pragma unroll
  for (int i = 0; i < 8; ++i) {
    float4 v0 = {acc[i][0], acc[i][1], acc[i][2], acc[i][3]};
    float4 v1 = {acc[i][4], acc[i][5], acc[i][6], acc[i][7]};
    size_t off = (size_t)(brow + tm + i) * OUT_DIM + bcol + tn;
    *(float4*)&C[off]     = v0;
    *(float4*)&C[off + 4] = v1;
  }
}

// ---------------- coords: G = h @ Wg^T in float64 + packed f32 copy ----
__global__ __launch_bounds__(256) void coords_kernel(
    const float* __restrict__ h, const float* __restrict__ Wg,
    double* __restrict__ Gx, double* __restrict__ Gy,
    double* __restrict__ Gz, double* __restrict__ Gsq,
    float4* __restrict__ gpk) {
  int node = (blockIdx.x * blockDim.x + threadIdx.x) >> 6;
  int lane = threadIdx.x & 63;
  if (node >= N_NODES) return;
  const float* hr = h + (size_t)node * IN_DIM;
  double s0 = 0.0, s1 = 0.0, s2 = 0.0;
  for (int k = lane; k < IN_DIM; k += 64) {
    double hv = (double)hr[k];
    s0 += hv * (double)Wg[0 * IN_DIM + k];
    s1 += hv * (double)Wg[1 * IN_DIM + k];
    s2 += hv * (double)Wg[2 * IN_DIM + k];
  }
  #pragma unroll
  for (int off = 32; off; off >>= 1) {
    s0 += __shfl_down(s0, off);
    s1 += __shfl_down(s1, off);
    s2 += __shfl_down(s2, off);
  }
  if (lane == 0) {
    double sq = s0 * s0 + s1 * s1 + s2 * s2;
    Gx[node] = s0; Gy[node] = s1; Gz[node] = s2; Gsq[node] = sq;
    gpk[node] = make_float4((float)s0, (float)s1, (float)s2, (float)sq);
  }
}

// identical f32 score in both scan phases (fixed fma contraction order)
__device__ __forceinline__ float negd2_f32(float4 a, float4 b) {
  float d = fmaf(a.x, b.x, fmaf(a.y, b.y, a.z * b.z));
  return fmaf(2.f, d, -a.w - b.w);
}

// ---------------- knn: 4 queries per block, threshold-select ----------------
__global__ __launch_bounds__(256) void knn_kernel(
    const float4* __restrict__ gpk,
    const double* __restrict__ Gx, const double* __restrict__ Gy,
    const double* __restrict__ Gz, const double* __restrict__ Gsq,
    int* __restrict__ knn) {
  const int tid   = threadIdx.x;
  const int wv    = tid >> 6;
  const int lane  = tid & 63;
  const int qbase = blockIdx.x * 4;

  __shared__ float s_tmax[4][256];
  __shared__ float s_T[4];
  __shared__ int   s_cand[4][CAP];
  __shared__ int   s_cnt[4];

  float4 qp[4];
  #pragma unroll
  for (int s = 0; s < 4; ++s) qp[s] = gpk[qbase + s];

  // Phase A: branchless scan, per-thread maxima for the 4 queries
  float tmax[4] = {-1e30f, -1e30f, -1e30f, -1e30f};
  for (int i = 0; i < 32; ++i) {
    int j = tid + (i << 8);
    float4 c = gpk[j];
    #pragma unroll
    for (int s = 0; s < 4; ++s) tmax[s] = fmaxf(tmax[s], negd2_f32(qp[s], c));
  }
  #pragma unroll
  for (int s = 0; s < 4; ++s) s_tmax[s][tid] = tmax[s];
  if (tid < 4) s_cnt[tid] = 0;
  __syncthreads();

  // Phase B: wave wv -> T[wv] = 16th largest of 64 per-lane maxima (each
  // lane-max covers 128 distinct candidates => >=16 candidates >= T).
  {
    float m0 = s_tmax[wv][lane * 4 + 0];
    float m1 = s_tmax[wv][lane * 4 + 1];
    float m2 = s_tmax[wv][lane * 4 + 2];
    float m3 = s_tmax[wv][lane * 4 + 3];
    float cur = fmaxf(fmaxf(m0, m1), fmaxf(m2, m3));
    float T = cur;
    for (int t = 0; t < KN; ++t) {
      float bv = cur; int bl = lane;
      #pragma unroll
      for (int off = 32; off; off >>= 1) {
        float ov = __shfl_xor(bv, off);
        int   ol = __shfl_xor(bl, off);
        if (ov > bv) { bv = ov; bl = ol; }
      }
      T = bv;
      if (lane == bl) cur = -1e30f;
    }
    if (lane == 0) s_T[wv] = T;
  }
  __syncthreads();

  // Phase C: rescan, collect candidates >= T per query
  float Ts[4];
  #pragma unroll
  for (int s = 0; s < 4; ++s) Ts[s] = s_T[s];
  for (int i = 0; i < 32; ++i) {
    int j = tid + (i << 8);
    float4 c = gpk[j];
    #pragma unroll
    for (int s = 0; s < 4; ++s) {
      float neg = negd2_f32(qp[s], c);
      if (neg >= Ts[s]) {
        int p = atomicAdd(&s_cnt[s], 1);
        if (p < CAP) s_cand[s][p] = j;
      }
    }
  }
  __syncthreads();

  // Phase D: wave wv exact-ranks query qbase+wv's candidates in f64
  {
    int q   = qbase + wv;
    int cnt = s_cnt[wv]; if (cnt > CAP) cnt = CAP;
    double xi = Gx[q], yi = Gy[q], zi = Gz[q], sqi = Gsq[q];

    double va = -1e300, vb = -1e300;
    int    ja = 0x7fffffff, jb = 0x7fffffff;
    if (lane < cnt) {
      int j = s_cand[wv][lane];
      va = 2.0 * (xi * Gx[j] + yi * Gy[j] + zi * Gz[j]) - sqi - Gsq[j];
      ja = j;
    }
    if (lane + 64 < cnt) {
      int j = s_cand[wv][lane + 64];
      vb = 2.0 * (xi * Gx[j] + yi * Gy[j] + zi * Gz[j]) - sqi - Gsq[j];
      jb = j;
    }
    if (vb > va || (vb == va && jb < ja)) {
      double tv = va; va = vb; vb = tv;
      int ti = ja; ja = jb; jb = ti;
    }

    for (int t = 0; t < KN; ++t) {
      double bv = va; int bj = ja; int bl = lane;
      #pragma unroll
      for (int off = 32; off; off >>= 1) {
        double ov = __shfl_xor(bv, off);
        int    oj = __shfl_xor(bj, off);
        int    ol = __shfl_xor(bl, off);
        if (ov > bv || (ov == bv && oj < bj)) { bv = ov; bj = oj; bl = ol; }
      }
      if (lane == 0) knn[q * KN + t] = bj;
      if (lane == bl) { va = vb; ja = jb; vb = -1e300; jb = 0x7fffffff; }
    }
  }
}

// ---------------- attend: per dst node, 16 neighbors ----------------
__global__ __launch_bounds__(256) void attend_kernel(
    const float* __restrict__ Q, const float* __restrict__ Km, const float* __restrict__ V,
    const double* __restrict__ Gx, const double* __restrict__ Gy, const double* __restrict__ Gz,
    const int* __restrict__ knn, float* __restrict__ out) {
  const int i    = blockIdx.x;
  const int tid  = threadIdx.x;
  const int wv   = tid >> 6;
  const int lane = tid & 63;

  __shared__ int   s_idx[KN];
  __shared__ float s_w[KN];
  __shared__ float s_se[KN];

  if (tid < KN) s_idx[tid] = knn[i * KN + tid];
  __syncthreads();

  const float* qr = Q + (size_t)i * OUT_DIM;
  float partial[4];
  #pragma unroll
  for (int s = 0; s < 4; ++s) {
    int src = s_idx[wv * 4 + s];
    const float* kr = Km + (size_t)src * OUT_DIM;
    float acc = 0.f;
    for (int d = lane; d < OUT_DIM; d += 64) acc = fmaf(kr[d], qr[d], acc);
    partial[s] = acc;
  }
  #pragma unroll
  for (int s = 0; s < 4; ++s)
    #pragma unroll
    for (int off = 32; off; off >>= 1) partial[s] += __shfl_down(partial[s], off);

  if (lane == 0) {
    const double xi = Gx[i], yi = Gy[i], zi = Gz[i];
    #pragma unroll
    for (int s = 0; s < 4; ++s) {
      int e = wv * 4 + s;
      int src = s_idx[e];
      float sc = partial[s] / 22.627417f;
      sc = fminf(fmaxf(sc, -5.f), 5.f);
      float se = expf(sc);
      double dx = Gx[src] - xi, dy = Gy[src] - yi, dz = Gz[src] - zi;
      double dd = -sqrt(dx * dx + dy * dy + dz * dz + 1e-6);
      double dc = fmin(fmax(dd / 22.627416997969522, -5.0), 5.0);
      float de = (float)exp(dc);
      s_se[e] = se;
      s_w[e]  = se * de;
    }
  }
  __syncthreads();

  float z = 0.f;
  #pragma unroll
  for (int e = 0; e < KN; ++e) z += s_se[e];

  for (int d = tid; d < OUT_DIM; d += 256) {
    float acc = 0.f;
    #pragma unroll
    for (int e = 0; e < KN; ++e)
      acc = fmaf(s_w[e], V[(size_t)s_idx[e] * OUT_DIM + d], acc);
    out[(size_t)i * OUT_DIM + d] = (z > 0.f) ? (acc / z) : acc;
  }
}

extern "C" void kernel_launch(void* const* d_in, const int* in_sizes, int n_in,
                              void* d_out, int out_size, void* d_ws, size_t ws_size,
                              hipStream_t stream) {
  const float* h  = (const float*)d_in[0];
  const float* Wq = (const float*)d_in[1];
  const float* Wk = (const float*)d_in[2];
  const float* Wv = (const float*)d_in[3];
  const float* Wg = (const float*)d_in[4];
  float* out = (float*)d_out;

  char* ws = (char*)d_ws;
  float* Q = (float*)ws;
  float* K = Q + (size_t)N_NODES * OUT_DIM;
  float* V = K + (size_t)N_NODES * OUT_DIM;
  double* Gx  = (double*)(V + (size_t)N_NODES * OUT_DIM);
  double* Gy  = Gx + N_NODES;
  double* Gz  = Gy + N_NODES;
  double* Gsq = Gz + N_NODES;
  int* knn = (int*)(Gsq + N_NODES);
  float4* gpk = (float4*)(knn + (size_t)N_NODES * KN);

  dim3 gemm_grid(OUT_DIM / BN, N_NODES / BM, 3);
  hipLaunchKernelGGL(proj_gemm, gemm_grid, dim3(256), 0, stream,
                     h, Wq, Wk, Wv, Q, K, V);
  hipLaunchKernelGGL(coords_kernel, dim3(N_NODES / 4), dim3(256), 0, stream,
                     h, Wg, Gx, Gy, Gz, Gsq, gpk);
  hipLaunchKernelGGL(knn_kernel, dim3(N_NODES / 4), dim3(256), 0, stream,
                     gpk, Gx, Gy, Gz, Gsq, knn);
  hipLaunchKernelGGL(attend_kernel, dim3(N_NODES), dim3(256), 0, stream,
                     Q, K, V, Gx, Gy, Gz, knn, out);
}

// Round 3
// 150.391 us; speedup vs baseline: 3.6819x; 2.1058x over previous
//
#include <hip/hip_runtime.h>
#include <hip/hip_bf16.h>
#include <math.h>

#define N_NODES 8192
#define IN_DIM  512
#define OUT_DIM 512
#define KN      16
#define CAP     128

typedef __attribute__((ext_vector_type(8))) short bf16x8;
typedef __attribute__((ext_vector_type(4))) float f32x4;

__device__ __forceinline__ ushort f2bf(float x) {
  __hip_bfloat16 b = __float2bfloat16(x);
  return *reinterpret_cast<ushort*>(&b);
}
__device__ __forceinline__ float bflo(unsigned u) { return __uint_as_float(u << 16); }
__device__ __forceinline__ float bfhi(unsigned u) { return __uint_as_float(u & 0xffff0000u); }

#define GLOAD_LDS16(gp, lp)                                                     \
  __builtin_amdgcn_global_load_lds((const __attribute__((address_space(1))) void*)(gp), \
                                   (__attribute__((address_space(3))) void*)(lp), 16, 0, 0)

// ---------------- split h -> A2 = [hi | lo] bf16, K'=1024 ----------------
__global__ __launch_bounds__(256) void split_h(const float* __restrict__ h,
                                               ushort* __restrict__ A2) {
  int i = blockIdx.x * 256 + threadIdx.x;      // float4 index, 8192*512/4 total
  float4 v = ((const float4*)h)[i];
  int m  = i >> 7;
  int kc = (i & 127) << 2;
  ushort h0 = f2bf(v.x), h1 = f2bf(v.y), h2 = f2bf(v.z), h3 = f2bf(v.w);
  ushort l0 = f2bf(v.x - bflo((unsigned)h0 << 0 | 0u) * 0.f - (v.x - (v.x - bflo((unsigned)h0)))); // placeholder avoided below
  // compute residuals cleanly
  float r0 = v.x - bflo((unsigned)h0);
  float r1 = v.y - bflo((unsigned)h1);
  float r2 = v.z - bflo((unsigned)h2);
  float r3 = v.w - bflo((unsigned)h3);
  ushort4 hi = make_ushort4(h0, h1, h2, h3);
  ushort4 lo = make_ushort4(f2bf(r0), f2bf(r1), f2bf(r2), f2bf(r3));
  *(ushort4*)&A2[(size_t)m * 1024 + kc]       = hi;
  *(ushort4*)&A2[(size_t)m * 1024 + 512 + kc] = lo;
}

// ---------------- split W -> B2 = [hi | hi] bf16 (rows: Wq,Wk,Wv) --------
__global__ __launch_bounds__(256) void split_w(const float* __restrict__ Wq,
                                               const float* __restrict__ Wk,
                                               const float* __restrict__ Wv,
                                               ushort* __restrict__ B2) {
  int i = blockIdx.x * 256 + threadIdx.x;      // float4 index, 1536*512/4 total
  int n  = i >> 7;
  int kc = (i & 127) << 2;
  const float* W = (n < 512) ? Wq : (n < 1024) ? Wk : Wv;
  int r = n & 511;
  float4 v = *(const float4*)&W[(size_t)r * 512 + kc];
  ushort4 hv = make_ushort4(f2bf(v.x), f2bf(v.y), f2bf(v.z), f2bf(v.w));
  *(ushort4*)&B2[(size_t)n * 1024 + kc]       = hv;
  *(ushort4*)&B2[(size_t)n * 1024 + 512 + kc] = hv;
}

// ---------------- fused Q/K/V bf16 MFMA GEMM (m97 structure) -------------
// C[8192x1536] = A2[8192x1024] * B2[1536x1024]^T, written bf16 to Q2/K2/V2
__global__ __launch_bounds__(256) void gemm_qkv(
    const ushort* __restrict__ A2, const ushort* __restrict__ B2,
    ushort* __restrict__ Q2, ushort* __restrict__ K2, ushort* __restrict__ V2) {
  __shared__ ushort lA[128 * 32];
  __shared__ ushort lB[128 * 32];
  const int tid = threadIdx.x, w = tid >> 6, lane = tid & 63;
  const int id = blockIdx.x;
  const int sw = (id & 7) * 96 + (id >> 3);     // XCD-contiguous (768 % 8 == 0)
  const int bm = sw / 12, bn = sw % 12;
  const int wr = w >> 1, wc = w & 1;

  f32x4 acc[4][4] = {};

  const int   srow = w * 32 + (lane >> 2);
  const int   scol = (lane & 3) * 8;
  const size_t gA0 = (size_t)(bm * 128 + srow) * 1024 + scol;
  const size_t gB0 = (size_t)(bn * 128 + srow) * 1024 + scol;

  for (int k0 = 0; k0 < 1024; k0 += 32) {
    GLOAD_LDS16(&A2[gA0 + k0],             &lA[w * 1024]);
    GLOAD_LDS16(&A2[gA0 + 16 * 1024 + k0], &lA[w * 1024 + 512]);
    GLOAD_LDS16(&B2[gB0 + k0],             &lB[w * 1024]);
    GLOAD_LDS16(&B2[gB0 + 16 * 1024 + k0], &lB[w * 1024 + 512]);
    __syncthreads();

    const int ar = wr * 64 + (lane & 15);
    const int br = wc * 64 + (lane & 15);
    const int kc = (lane >> 4) * 8;
    bf16x8 af[4], bfr[4];
    #pragma unroll
    for (int f = 0; f < 4; ++f) {
      af[f]  = *(const bf16x8*)&lA[(ar + f * 16) * 32 + kc];
      bfr[f] = *(const bf16x8*)&lB[(br + f * 16) * 32 + kc];
    }
    #pragma unroll
    for (int fm = 0; fm < 4; ++fm)
      #pragma unroll
      for (int fn = 0; fn < 4; ++fn)
        acc[fm][fn] = __builtin_amdgcn_mfma_f32_16x16x32_bf16(af[fm], bfr[fn], acc[fm][fn], 0, 0, 0);
    __syncthreads();
  }

  ushort* Cm = (bn < 4) ? Q2 : (bn < 8) ? K2 : V2;
  const int col  = (bn & 3) * 128 + wc * 64 + (lane & 15);
  const int row0 = bm * 128 + wr * 64 + (lane >> 4) * 4;
  #pragma unroll
  for (int fm = 0; fm < 4; ++fm)
    #pragma unroll
    for (int fn = 0; fn < 4; ++fn)
      #pragma unroll
      for (int r = 0; r < 4; ++r)
        Cm[(size_t)(row0 + fm * 16 + r) * 512 + col + fn * 16] = f2bf(acc[fm][fn][r]);
}

// ---------------- coords: G = h @ Wg^T in float64 + packed f32 copy ----
__global__ __launch_bounds__(256) void coords_kernel(
    const float* __restrict__ h, const float* __restrict__ Wg,
    double* __restrict__ Gx, double* __restrict__ Gy,
    double* __restrict__ Gz, double* __restrict__ Gsq,
    float4* __restrict__ gpk) {
  int node = (blockIdx.x * blockDim.x + threadIdx.x) >> 6;
  int lane = threadIdx.x & 63;
  if (node >= N_NODES) return;
  const float* hr = h + (size_t)node * IN_DIM;
  double s0 = 0.0, s1 = 0.0, s2 = 0.0;
  for (int k = lane; k < IN_DIM; k += 64) {
    double hv = (double)hr[k];
    s0 += hv * (double)Wg[0 * IN_DIM + k];
    s1 += hv * (double)Wg[1 * IN_DIM + k];
    s2 += hv * (double)Wg[2 * IN_DIM + k];
  }
  #pragma unroll
  for (int off = 32; off; off >>= 1) {
    s0 += __shfl_down(s0, off);
    s1 += __shfl_down(s1, off);
    s2 += __shfl_down(s2, off);
  }
  if (lane == 0) {
    double sq = s0 * s0 + s1 * s1 + s2 * s2;
    Gx[node] = s0; Gy[node] = s1; Gz[node] = s2; Gsq[node] = sq;
    gpk[node] = make_float4((float)s0, (float)s1, (float)s2, (float)sq);
  }
}

__device__ __forceinline__ float negd2_f32(float4 a, float4 b) {
  float d = fmaf(a.x, b.x, fmaf(a.y, b.y, a.z * b.z));
  return fmaf(2.f, d, -a.w - b.w);
}

// ---------------- knn: 4 queries per block, threshold-select -------------
__global__ __launch_bounds__(256) void knn_kernel(
    const float4* __restrict__ gpk,
    const double* __restrict__ Gx, const double* __restrict__ Gy,
    const double* __restrict__ Gz, const double* __restrict__ Gsq,
    int* __restrict__ knn) {
  const int tid   = threadIdx.x;
  const int wv    = tid >> 6;
  const int lane  = tid & 63;
  const int qbase = blockIdx.x * 4;

  __shared__ float s_tmax[4][256];
  __shared__ float s_T[4];
  __shared__ int   s_cand[4][CAP];
  __shared__ int   s_cnt[4];

  float4 qp[4];
  #pragma unroll
  for (int s = 0; s < 4; ++s) qp[s] = gpk[qbase + s];

  float tmax[4] = {-1e30f, -1e30f, -1e30f, -1e30f};
  for (int i = 0; i < 32; ++i) {
    int j = tid + (i << 8);
    float4 c = gpk[j];
    #pragma unroll
    for (int s = 0; s < 4; ++s) tmax[s] = fmaxf(tmax[s], negd2_f32(qp[s], c));
  }
  #pragma unroll
  for (int s = 0; s < 4; ++s) s_tmax[s][tid] = tmax[s];
  if (tid < 4) s_cnt[tid] = 0;
  __syncthreads();

  {
    float m0 = s_tmax[wv][lane * 4 + 0];
    float m1 = s_tmax[wv][lane * 4 + 1];
    float m2 = s_tmax[wv][lane * 4 + 2];
    float m3 = s_tmax[wv][lane * 4 + 3];
    float cur = fmaxf(fmaxf(m0, m1), fmaxf(m2, m3));
    float T = cur;
    for (int t = 0; t < KN; ++t) {
      float bv = cur; int bl = lane;
      #pragma unroll
      for (int off = 32; off; off >>= 1) {
        float ov = __shfl_xor(bv, off);
        int   ol = __shfl_xor(bl, off);
        if (ov > bv) { bv = ov; bl = ol; }
      }
      T = bv;
      if (lane == bl) cur = -1e30f;
    }
    if (lane == 0) s_T[wv] = T;
  }
  __syncthreads();

  float Ts[4];
  #pragma unroll
  for (int s = 0; s < 4; ++s) Ts[s] = s_T[s];
  for (int i = 0; i < 32; ++i) {
    int j = tid + (i << 8);
    float4 c = gpk[j];
    #pragma unroll
    for (int s = 0; s < 4; ++s) {
      float neg = negd2_f32(qp[s], c);
      if (neg >= Ts[s]) {
        int p = atomicAdd(&s_cnt[s], 1);
        if (p < CAP) s_cand[s][p] = j;
      }
    }
  }
  __syncthreads();

  {
    int q   = qbase + wv;
    int cnt = s_cnt[wv]; if (cnt > CAP) cnt = CAP;
    double xi = Gx[q], yi = Gy[q], zi = Gz[q], sqi = Gsq[q];

    double va = -1e300, vb = -1e300;
    int    ja = 0x7fffffff, jb = 0x7fffffff;
    if (lane < cnt) {
      int j = s_cand[wv][lane];
      va = 2.0 * (xi * Gx[j] + yi * Gy[j] + zi * Gz[j]) - sqi - Gsq[j];
      ja = j;
    }
    if (lane + 64 < cnt) {
      int j = s_cand[wv][lane + 64];
      vb = 2.0 * (xi * Gx[j] + yi * Gy[j] + zi * Gz[j]) - sqi - Gsq[j];
      jb = j;
    }
    if (vb > va || (vb == va && jb < ja)) {
      double tv = va; va = vb; vb = tv;
      int ti = ja; ja = jb; jb = ti;
    }

    for (int t = 0; t < KN; ++t) {
      double bv = va; int bj = ja; int bl = lane;
      #pragma unroll
      for (int off = 32; off; off >>= 1) {
        double ov = __shfl_xor(bv, off);
        int    oj = __shfl_xor(bj, off);
        int    ol = __shfl_xor(bl, off);
        if (ov > bv || (ov == bv && oj < bj)) { bv = ov; bj = oj; bl = ol; }
      }
      if (lane == 0) knn[q * KN + t] = bj;
      if (lane == bl) { va = vb; ja = jb; vb = -1e300; jb = 0x7fffffff; }
    }
  }
}

// ---------------- attend: per dst node, 16 neighbors, bf16 Q/K/V ---------
__global__ __launch_bounds__(256) void attend_kernel(
    const ushort* __restrict__ Q2, const ushort* __restrict__ K2, const ushort* __restrict__ V2,
    const double* __restrict__ Gx, const double* __restrict__ Gy, const double* __restrict__ Gz,
    const int* __restrict__ knn, float* __restrict__ out) {
  const int i    = blockIdx.x;
  const int tid  = threadIdx.x;
  const int wv   = tid >> 6;
  const int lane = tid & 63;

  __shared__ int   s_idx[KN];
  __shared__ float s_w[KN];
  __shared__ float s_se[KN];

  if (tid < KN) s_idx[tid] = knn[i * KN + tid];
  __syncthreads();

  uint4 qa = *(const uint4*)&Q2[(size_t)i * 512 + lane * 8];
  float q0 = bflo(qa.x), q1 = bfhi(qa.x), q2 = bflo(qa.y), q3 = bfhi(qa.y);
  float q4 = bflo(qa.z), q5 = bfhi(qa.z), q6 = bflo(qa.w), q7 = bfhi(qa.w);

  float partial[4];
  #pragma unroll
  for (int s = 0; s < 4; ++s) {
    int src = s_idx[wv * 4 + s];
    uint4 ka = *(const uint4*)&K2[(size_t)src * 512 + lane * 8];
    float acc = q0 * bflo(ka.x);
    acc = fmaf(q1, bfhi(ka.x), acc);
    acc = fmaf(q2, bflo(ka.y), acc);
    acc = fmaf(q3, bfhi(ka.y), acc);
    acc = fmaf(q4, bflo(ka.z), acc);
    acc = fmaf(q5, bfhi(ka.z), acc);
    acc = fmaf(q6, bflo(ka.w), acc);
    acc = fmaf(q7, bfhi(ka.w), acc);
    partial[s] = acc;
  }
  #pragma unroll
  for (int s = 0; s < 4; ++s)
    #pragma unroll
    for (int off = 32; off; off >>= 1) partial[s] += __shfl_down(partial[s], off);

  if (lane == 0) {
    const double xi = Gx[i], yi = Gy[i], zi = Gz[i];
    #pragma unroll
    for (int s = 0; s < 4; ++s) {
      int e = wv * 4 + s;
      int src = s_idx[e];
      float sc = partial[s] / 22.627417f;
      sc = fminf(fmaxf(sc, -5.f), 5.f);
      float se = expf(sc);
      double dx = Gx[src] - xi, dy = Gy[src] - yi, dz = Gz[src] - zi;
      double dd = -sqrt(dx * dx + dy * dy + dz * dz + 1e-6);
      double dc = fmin(fmax(dd / 22.627416997969522, -5.0), 5.0);
      float de = (float)exp(dc);
      s_se[e] = se;
      s_w[e]  = se * de;
    }
  }
  __syncthreads();

  float z = 0.f;
  #pragma unroll
  for (int e = 0; e < KN; ++e) z += s_se[e];

  const int d = tid * 2;
  float a0 = 0.f, a1 = 0.f;
  #pragma unroll
  for (int e = 0; e < KN; ++e) {
    unsigned vv = *(const unsigned*)&V2[(size_t)s_idx[e] * 512 + d];
    a0 = fmaf(s_w[e], bflo(vv), a0);
    a1 = fmaf(s_w[e], bfhi(vv), a1);
  }
  float inv = (z > 0.f) ? (1.f / z) : 1.f;
  float2 o = make_float2(a0 * inv, a1 * inv);
  *(float2*)&out[(size_t)i * 512 + d] = o;
}

extern "C" void kernel_launch(void* const* d_in, const int* in_sizes, int n_in,
                              void* d_out, int out_size, void* d_ws, size_t ws_size,
                              hipStream_t stream) {
  const float* h  = (const float*)d_in[0];
  const float* Wq = (const float*)d_in[1];
  const float* Wk = (const float*)d_in[2];
  const float* Wv = (const float*)d_in[3];
  const float* Wg = (const float*)d_in[4];
  float* out = (float*)d_out;

  char* ws = (char*)d_ws;
  ushort* A2 = (ushort*)(ws);                          // 16 MB
  ushort* B2 = (ushort*)(ws + (16u << 20));            // 3 MB
  ushort* Q2 = (ushort*)(ws + (19u << 20));            // 8 MB
  ushort* K2 = (ushort*)(ws + (27u << 20));            // 8 MB
  ushort* V2 = (ushort*)(ws + (35u << 20));            // 8 MB
  float4* gpk = (float4*)(ws + (43u << 20));           // 128 KB
  double* Gx  = (double*)(ws + (43u << 20) + (1u << 17));
  double* Gy  = Gx + N_NODES;
  double* Gz  = Gy + N_NODES;
  double* Gsq = Gz + N_NODES;
  int*    knn = (int*)(Gsq + N_NODES);                 // 512 KB

  hipLaunchKernelGGL(split_h, dim3(4096), dim3(256), 0, stream, h, A2);
  hipLaunchKernelGGL(split_w, dim3(768), dim3(256), 0, stream, Wq, Wk, Wv, B2);
  hipLaunchKernelGGL(coords_kernel, dim3(N_NODES / 4), dim3(256), 0, stream,
                     h, Wg, Gx, Gy, Gz, Gsq, gpk);
  hipLaunchKernelGGL(gemm_qkv, dim3(768), dim3(256), 0, stream,
                     A2, B2, Q2, K2, V2);
  hipLaunchKernelGGL(knn_kernel, dim3(N_NODES / 4), dim3(256), 0, stream,
                     gpk, Gx, Gy, Gz, Gsq, knn);
  hipLaunchKernelGGL(attend_kernel, dim3(N_NODES), dim3(256), 0, stream,
                     Q2, K2, V2, Gx, Gy, Gz, knn, out);
}

// Round 4
// 120.467 us; speedup vs baseline: 4.5965x; 1.2484x over previous
//
#include <hip/hip_runtime.h>
#include <hip/hip_bf16.h>
#include <math.h>

#define N_NODES 8192
#define IN_DIM  512
#define OUT_DIM 512
#define KN      16
#define CAP     128
#define QPB     8

typedef __attribute__((ext_vector_type(8))) short bf16x8;
typedef __attribute__((ext_vector_type(4))) float f32x4;

__device__ __forceinline__ ushort f2bf(float x) {
  __hip_bfloat16 b = __float2bfloat16(x);
  return *reinterpret_cast<ushort*>(&b);
}
__device__ __forceinline__ float bflo(unsigned u) { return __uint_as_float(u << 16); }
__device__ __forceinline__ float bfhi(unsigned u) { return __uint_as_float(u & 0xffff0000u); }

#define GLOAD_LDS16(gp, lp)                                                     \
  __builtin_amdgcn_global_load_lds((const __attribute__((address_space(1))) void*)(gp), \
                                   (__attribute__((address_space(3))) void*)(lp), 16, 0, 0)

// ---------------- split h -> A2 = [hi | lo] bf16, K'=1024 ----------------
__global__ __launch_bounds__(256) void split_h(const float* __restrict__ h,
                                               ushort* __restrict__ A2) {
  int i = blockIdx.x * 256 + threadIdx.x;
  float4 v = ((const float4*)h)[i];
  int m  = i >> 7;
  int kc = (i & 127) << 2;
  ushort h0 = f2bf(v.x), h1 = f2bf(v.y), h2 = f2bf(v.z), h3 = f2bf(v.w);
  float r0 = v.x - bflo((unsigned)h0);
  float r1 = v.y - bflo((unsigned)h1);
  float r2 = v.z - bflo((unsigned)h2);
  float r3 = v.w - bflo((unsigned)h3);
  ushort4 hi = make_ushort4(h0, h1, h2, h3);
  ushort4 lo = make_ushort4(f2bf(r0), f2bf(r1), f2bf(r2), f2bf(r3));
  *(ushort4*)&A2[(size_t)m * 1024 + kc]       = hi;
  *(ushort4*)&A2[(size_t)m * 1024 + 512 + kc] = lo;
}

// ---------------- split W -> B2 = [hi | hi] bf16 (rows: Wq,Wk,Wv) --------
__global__ __launch_bounds__(256) void split_w(const float* __restrict__ Wq,
                                               const float* __restrict__ Wk,
                                               const float* __restrict__ Wv,
                                               ushort* __restrict__ B2) {
  int i = blockIdx.x * 256 + threadIdx.x;
  int n  = i >> 7;
  int kc = (i & 127) << 2;
  const float* W = (n < 512) ? Wq : (n < 1024) ? Wk : Wv;
  int r = n & 511;
  float4 v = *(const float4*)&W[(size_t)r * 512 + kc];
  ushort4 hv = make_ushort4(f2bf(v.x), f2bf(v.y), f2bf(v.z), f2bf(v.w));
  *(ushort4*)&B2[(size_t)n * 1024 + kc]       = hv;
  *(ushort4*)&B2[(size_t)n * 1024 + 512 + kc] = hv;
}

// ---------------- fused Q/K/V bf16 MFMA GEMM (m97 structure) -------------
__global__ __launch_bounds__(256) void gemm_qkv(
    const ushort* __restrict__ A2, const ushort* __restrict__ B2,
    ushort* __restrict__ Q2, ushort* __restrict__ K2, ushort* __restrict__ V2) {
  __shared__ ushort lA[128 * 32];
  __shared__ ushort lB[128 * 32];
  const int tid = threadIdx.x, w = tid >> 6, lane = tid & 63;
  const int id = blockIdx.x;
  const int sw = (id & 7) * 96 + (id >> 3);
  const int bm = sw / 12, bn = sw % 12;
  const int wr = w >> 1, wc = w & 1;

  f32x4 acc[4][4] = {};

  const int   srow = w * 32 + (lane >> 2);
  const int   scol = (lane & 3) * 8;
  const size_t gA0 = (size_t)(bm * 128 + srow) * 1024 + scol;
  const size_t gB0 = (size_t)(bn * 128 + srow) * 1024 + scol;

  for (int k0 = 0; k0 < 1024; k0 += 32) {
    GLOAD_LDS16(&A2[gA0 + k0],             &lA[w * 1024]);
    GLOAD_LDS16(&A2[gA0 + 16 * 1024 + k0], &lA[w * 1024 + 512]);
    GLOAD_LDS16(&B2[gB0 + k0],             &lB[w * 1024]);
    GLOAD_LDS16(&B2[gB0 + 16 * 1024 + k0], &lB[w * 1024 + 512]);
    __syncthreads();

    const int ar = wr * 64 + (lane & 15);
    const int br = wc * 64 + (lane & 15);
    const int kc = (lane >> 4) * 8;
    bf16x8 af[4], bfr[4];
    #pragma unroll
    for (int f = 0; f < 4; ++f) {
      af[f]  = *(const bf16x8*)&lA[(ar + f * 16) * 32 + kc];
      bfr[f] = *(const bf16x8*)&lB[(br + f * 16) * 32 + kc];
    }
    #pragma unroll
    for (int fm = 0; fm < 4; ++fm)
      #pragma unroll
      for (int fn = 0; fn < 4; ++fn)
        acc[fm][fn] = __builtin_amdgcn_mfma_f32_16x16x32_bf16(af[fm], bfr[fn], acc[fm][fn], 0, 0, 0);
    __syncthreads();
  }

  ushort* Cm = (bn < 4) ? Q2 : (bn < 8) ? K2 : V2;
  const int col  = (bn & 3) * 128 + wc * 64 + (lane & 15);
  const int row0 = bm * 128 + wr * 64 + (lane >> 4) * 4;
  #pragma unroll
  for (int fm = 0; fm < 4; ++fm)
    #pragma unroll
    for (int fn = 0; fn < 4; ++fn)
      #pragma unroll
      for (int r = 0; r < 4; ++r)
        Cm[(size_t)(row0 + fm * 16 + r) * 512 + col + fn * 16] = f2bf(acc[fm][fn][r]);
}

// ---------------- coords: G = h @ Wg^T in float64 + packed f32 copy ------
// gpk = (x, y, z, -sq) so the knn score is 3 FMAs with init c.w
__global__ __launch_bounds__(256) void coords_kernel(
    const float* __restrict__ h, const float* __restrict__ Wg,
    double* __restrict__ Gx, double* __restrict__ Gy,
    double* __restrict__ Gz, double* __restrict__ Gsq,
    float4* __restrict__ gpk) {
  int node = (blockIdx.x * blockDim.x + threadIdx.x) >> 6;
  int lane = threadIdx.x & 63;
  if (node >= N_NODES) return;
  const float* hr = h + (size_t)node * IN_DIM;
  double s0 = 0.0, s1 = 0.0, s2 = 0.0;
  for (int k = lane; k < IN_DIM; k += 64) {
    double hv = (double)hr[k];
    s0 += hv * (double)Wg[0 * IN_DIM + k];
    s1 += hv * (double)Wg[1 * IN_DIM + k];
    s2 += hv * (double)Wg[2 * IN_DIM + k];
  }
  #pragma unroll
  for (int off = 32; off; off >>= 1) {
    s0 += __shfl_down(s0, off);
    s1 += __shfl_down(s1, off);
    s2 += __shfl_down(s2, off);
  }
  if (lane == 0) {
    double sq = s0 * s0 + s1 * s1 + s2 * s2;
    Gx[node] = s0; Gy[node] = s1; Gz[node] = s2; Gsq[node] = sq;
    gpk[node] = make_float4((float)s0, (float)s1, (float)s2, -(float)sq);
  }
}

// ---------------- knn: 8 queries/block, radix-select threshold -----------
__global__ __launch_bounds__(256) void knn_kernel(
    const float4* __restrict__ gpk,
    const double* __restrict__ Gx, const double* __restrict__ Gy,
    const double* __restrict__ Gz, const double* __restrict__ Gsq,
    int* __restrict__ knn) {
  const int tid   = threadIdx.x;
  const int w     = tid >> 6;
  const int lane  = tid & 63;
  const int qbase = blockIdx.x * QPB;

  __shared__ float  s_tmax[QPB][256];
  __shared__ int    s_cand[QPB][CAP];
  __shared__ double s_dval[QPB][CAP];
  __shared__ int    s_cnt[QPB];
  __shared__ float  s_T[QPB];

  float q2x[QPB], q2y[QPB], q2z[QPB], tmax[QPB];
  #pragma unroll
  for (int s = 0; s < QPB; ++s) {
    float4 qv = gpk[qbase + s];
    q2x[s] = 2.f * qv.x; q2y[s] = 2.f * qv.y; q2z[s] = 2.f * qv.z;
    tmax[s] = -1e30f;
  }
  if (tid < QPB) s_cnt[tid] = 0;

  // Phase A: branchless max scan (3 FMA + shared max3 per pair)
  for (int i = 0; i < 16; ++i) {
    float4 c0 = gpk[tid + i * 512];
    float4 c1 = gpk[tid + i * 512 + 256];
    #pragma unroll
    for (int s = 0; s < QPB; ++s) {
      float v0 = fmaf(q2x[s], c0.x, fmaf(q2y[s], c0.y, fmaf(q2z[s], c0.z, c0.w)));
      float v1 = fmaf(q2x[s], c1.x, fmaf(q2y[s], c1.y, fmaf(q2z[s], c1.z, c1.w)));
      tmax[s] = fmaxf(fmaxf(tmax[s], v0), v1);
    }
  }
  #pragma unroll
  for (int s = 0; s < QPB; ++s) s_tmax[s][tid] = tmax[s];
  __syncthreads();

  // Phase B: wave w handles queries 2w, 2w+1. Exact 16th-of-64 via radix
  // select on order-preserving float->uint map (ballot+popcount per bit).
  #pragma unroll
  for (int qq = 0; qq < 2; ++qq) {
    int q = w * 2 + qq;
    float v = fmaxf(fmaxf(s_tmax[q][lane], s_tmax[q][lane + 64]),
                    fmaxf(s_tmax[q][lane + 128], s_tmax[q][lane + 192]));
    unsigned b = __float_as_uint(v);
    unsigned u = b ^ ((unsigned)((int)b >> 31) | 0x80000000u);
    unsigned thr = 0;
    for (int bit = 31; bit >= 0; --bit) {
      unsigned cand = thr | (1u << bit);
      unsigned long long m = __ballot(u >= cand);
      if (__popcll(m) >= KN) thr = cand;
    }
    unsigned tb = (thr & 0x80000000u) ? (thr ^ 0x80000000u) : ~thr;
    if (lane == 0) s_T[q] = __uint_as_float(tb);
  }
  __syncthreads();

  // Phase C: rescan (identical FMA chain), collect candidates >= T
  float Ts[QPB];
  #pragma unroll
  for (int s = 0; s < QPB; ++s) Ts[s] = s_T[s];
  for (int i = 0; i < 16; ++i) {
    int j0 = tid + i * 512, j1 = j0 + 256;
    float4 c0 = gpk[j0];
    float4 c1 = gpk[j1];
    #pragma unroll
    for (int s = 0; s < QPB; ++s) {
      float v0 = fmaf(q2x[s], c0.x, fmaf(q2y[s], c0.y, fmaf(q2z[s], c0.z, c0.w)));
      float v1 = fmaf(q2x[s], c1.x, fmaf(q2y[s], c1.y, fmaf(q2z[s], c1.z, c1.w)));
      if (v0 >= Ts[s]) { int p = atomicAdd(&s_cnt[s], 1); if (p < CAP) s_cand[s][p] = j0; }
      if (v1 >= Ts[s]) { int p = atomicAdd(&s_cnt[s], 1); if (p < CAP) s_cand[s][p] = j1; }
    }
  }
  __syncthreads();

  // Phase D: exact f64 scores for collected candidates, rank-by-counting
  const int qA = w * 2, qB = qA + 1;
  const int cntA = min(s_cnt[qA], CAP);
  const int cntB = min(s_cnt[qB], CAP);
  int j0a = -1, j1a = -1, j0b = -1, j1b = -1;
  double v0a = 0, v1a = 0, v0b = 0, v1b = 0;
  {
    int gq = qbase + qA;
    double xi = Gx[gq], yi = Gy[gq], zi = Gz[gq], sqi = Gsq[gq];
    if (lane < cntA) {
      j0a = s_cand[qA][lane];
      v0a = 2.0 * (xi * Gx[j0a] + yi * Gy[j0a] + zi * Gz[j0a]) - sqi - Gsq[j0a];
      s_dval[qA][lane] = v0a;
    }
    if (lane + 64 < cntA) {
      j1a = s_cand[qA][lane + 64];
      v1a = 2.0 * (xi * Gx[j1a] + yi * Gy[j1a] + zi * Gz[j1a]) - sqi - Gsq[j1a];
      s_dval[qA][lane + 64] = v1a;
    }
  }
  {
    int gq = qbase + qB;
    double xi = Gx[gq], yi = Gy[gq], zi = Gz[gq], sqi = Gsq[gq];
    if (lane < cntB) {
      j0b = s_cand[qB][lane];
      v0b = 2.0 * (xi * Gx[j0b] + yi * Gy[j0b] + zi * Gz[j0b]) - sqi - Gsq[j0b];
      s_dval[qB][lane] = v0b;
    }
    if (lane + 64 < cntB) {
      j1b = s_cand[qB][lane + 64];
      v1b = 2.0 * (xi * Gx[j1b] + yi * Gy[j1b] + zi * Gz[j1b]) - sqi - Gsq[j1b];
      s_dval[qB][lane + 64] = v1b;
    }
  }
  __syncthreads();
  {
    int r0 = 0, r1 = 0;
    for (int m = 0; m < cntA; ++m) {
      double dv = s_dval[qA][m]; int di = s_cand[qA][m];
      r0 += (dv > v0a) || (dv == v0a && di < j0a);
      r1 += (dv > v1a) || (dv == v1a && di < j1a);
    }
    int gq = qbase + qA;
    if (j0a >= 0 && r0 < KN) knn[gq * KN + r0] = j0a;
    if (j1a >= 0 && r1 < KN) knn[gq * KN + r1] = j1a;
  }
  {
    int r0 = 0, r1 = 0;
    for (int m = 0; m < cntB; ++m) {
      double dv = s_dval[qB][m]; int di = s_cand[qB][m];
      r0 += (dv > v0b) || (dv == v0b && di < j0b);
      r1 += (dv > v1b) || (dv == v1b && di < j1b);
    }
    int gq = qbase + qB;
    if (j0b >= 0 && r0 < KN) knn[gq * KN + r0] = j0b;
    if (j1b >= 0 && r1 < KN) knn[gq * KN + r1] = j1b;
  }
}

// ---------------- attend: per dst node, 16 neighbors, bf16 Q/K/V ---------
__global__ __launch_bounds__(256) void attend_kernel(
    const ushort* __restrict__ Q2, const ushort* __restrict__ K2, const ushort* __restrict__ V2,
    const double* __restrict__ Gx, const double* __restrict__ Gy, const double* __restrict__ Gz,
    const int* __restrict__ knn, float* __restrict__ out) {
  const int i    = blockIdx.x;
  const int tid  = threadIdx.x;
  const int wv   = tid >> 6;
  const int lane = tid & 63;

  __shared__ int   s_idx[KN];
  __shared__ float s_w[KN];
  __shared__ float s_se[KN];

  if (tid < KN) s_idx[tid] = knn[i * KN + tid];
  __syncthreads();

  uint4 qa = *(const uint4*)&Q2[(size_t)i * 512 + lane * 8];
  float q0 = bflo(qa.x), q1 = bfhi(qa.x), q2 = bflo(qa.y), q3 = bfhi(qa.y);
  float q4 = bflo(qa.z), q5 = bfhi(qa.z), q6 = bflo(qa.w), q7 = bfhi(qa.w);

  float partial[4];
  #pragma unroll
  for (int s = 0; s < 4; ++s) {
    int src = s_idx[wv * 4 + s];
    uint4 ka = *(const uint4*)&K2[(size_t)src * 512 + lane * 8];
    float acc = q0 * bflo(ka.x);
    acc = fmaf(q1, bfhi(ka.x), acc);
    acc = fmaf(q2, bflo(ka.y), acc);
    acc = fmaf(q3, bfhi(ka.y), acc);
    acc = fmaf(q4, bflo(ka.z), acc);
    acc = fmaf(q5, bfhi(ka.z), acc);
    acc = fmaf(q6, bflo(ka.w), acc);
    acc = fmaf(q7, bfhi(ka.w), acc);
    partial[s] = acc;
  }
  #pragma unroll
  for (int s = 0; s < 4; ++s)
    #pragma unroll
    for (int off = 32; off; off >>= 1) partial[s] += __shfl_down(partial[s], off);

  if (lane == 0) {
    const double xi = Gx[i], yi = Gy[i], zi = Gz[i];
    #pragma unroll
    for (int s = 0; s < 4; ++s) {
      int e = wv * 4 + s;
      int src = s_idx[e];
      float sc = partial[s] / 22.627417f;
      sc = fminf(fmaxf(sc, -5.f), 5.f);
      float se = expf(sc);
      double dx = Gx[src] - xi, dy = Gy[src] - yi, dz = Gz[src] - zi;
      double dd = -sqrt(dx * dx + dy * dy + dz * dz + 1e-6);
      double dc = fmin(fmax(dd / 22.627416997969522, -5.0), 5.0);
      float de = (float)exp(dc);
      s_se[e] = se;
      s_w[e]  = se * de;
    }
  }
  __syncthreads();

  float z = 0.f;
  #pragma unroll
  for (int e = 0; e < KN; ++e) z += s_se[e];

  const int d = tid * 2;
  float a0 = 0.f, a1 = 0.f;
  #pragma unroll
  for (int e = 0; e < KN; ++e) {
    unsigned vv = *(const unsigned*)&V2[(size_t)s_idx[e] * 512 + d];
    a0 = fmaf(s_w[e], bflo(vv), a0);
    a1 = fmaf(s_w[e], bfhi(vv), a1);
  }
  float inv = (z > 0.f) ? (1.f / z) : 1.f;
  float2 o = make_float2(a0 * inv, a1 * inv);
  *(float2*)&out[(size_t)i * 512 + d] = o;
}

extern "C" void kernel_launch(void* const* d_in, const int* in_sizes, int n_in,
                              void* d_out, int out_size, void* d_ws, size_t ws_size,
                              hipStream_t stream) {
  const float* h  = (const float*)d_in[0];
  const float* Wq = (const float*)d_in[1];
  const float* Wk = (const float*)d_in[2];
  const float* Wv = (const float*)d_in[3];
  const float* Wg = (const float*)d_in[4];
  float* out = (float*)d_out;

  char* ws = (char*)d_ws;
  ushort* A2 = (ushort*)(ws);
  ushort* B2 = (ushort*)(ws + (16u << 20));
  ushort* Q2 = (ushort*)(ws + (19u << 20));
  ushort* K2 = (ushort*)(ws + (27u << 20));
  ushort* V2 = (ushort*)(ws + (35u << 20));
  float4* gpk = (float4*)(ws + (43u << 20));
  double* Gx  = (double*)(ws + (43u << 20) + (1u << 17));
  double* Gy  = Gx + N_NODES;
  double* Gz  = Gy + N_NODES;
  double* Gsq = Gz + N_NODES;
  int*    knn = (int*)(Gsq + N_NODES);

  hipLaunchKernelGGL(split_h, dim3(4096), dim3(256), 0, stream, h, A2);
  hipLaunchKernelGGL(split_w, dim3(768), dim3(256), 0, stream, Wq, Wk, Wv, B2);
  hipLaunchKernelGGL(coords_kernel, dim3(N_NODES / 4), dim3(256), 0, stream,
                     h, Wg, Gx, Gy, Gz, Gsq, gpk);
  hipLaunchKernelGGL(gemm_qkv, dim3(768), dim3(256), 0, stream,
                     A2, B2, Q2, K2, V2);
  hipLaunchKernelGGL(knn_kernel, dim3(N_NODES / QPB), dim3(256), 0, stream,
                     gpk, Gx, Gy, Gz, Gsq, knn);
  hipLaunchKernelGGL(attend_kernel, dim3(N_NODES), dim3(256), 0, stream,
                     Q2, K2, V2, Gx, Gy, Gz, knn, out);
}

// Round 5
// 113.412 us; speedup vs baseline: 4.8824x; 1.0622x over previous
//
#include <hip/hip_runtime.h>
#include <hip/hip_bf16.h>
#include <math.h>

#define N_NODES 8192
#define IN_DIM  512
#define OUT_DIM 512
#define KN      16
#define CAP     128
#define QPB     8

typedef __attribute__((ext_vector_type(8))) short bf16x8;
typedef __attribute__((ext_vector_type(4))) float f32x4;

__device__ __forceinline__ ushort f2bf(float x) {
  __hip_bfloat16 b = __float2bfloat16(x);
  return *reinterpret_cast<ushort*>(&b);
}
__device__ __forceinline__ float bflo(unsigned u) { return __uint_as_float(u << 16); }
__device__ __forceinline__ float bfhi(unsigned u) { return __uint_as_float(u & 0xffff0000u); }

#define GLOAD_LDS16(gp, lp)                                                     \
  __builtin_amdgcn_global_load_lds((const __attribute__((address_space(1))) void*)(gp), \
                                   (__attribute__((address_space(3))) void*)(lp), 16, 0, 0)

// ---------------- prep: h -> A2 (hi|lo bf16) AND f64 G coords, one h pass ----
__global__ __launch_bounds__(256) void prep_kernel(
    const float* __restrict__ h, const float* __restrict__ Wg,
    ushort* __restrict__ A2,
    double* __restrict__ Gx, double* __restrict__ Gy,
    double* __restrict__ Gz, double* __restrict__ Gsq,
    float4* __restrict__ gpk) {
  const int node = (blockIdx.x * 256 + threadIdx.x) >> 6;
  const int lane = threadIdx.x & 63;
  const int k = lane * 8;
  const float* hr = h + (size_t)node * IN_DIM;

  float4 v0 = *(const float4*)&hr[k];
  float4 v1 = *(const float4*)&hr[k + 4];

  // bf16 hi/lo split
  ushort h0 = f2bf(v0.x), h1 = f2bf(v0.y), h2 = f2bf(v0.z), h3 = f2bf(v0.w);
  ushort h4 = f2bf(v1.x), h5 = f2bf(v1.y), h6 = f2bf(v1.z), h7 = f2bf(v1.w);
  ushort4 hiA = make_ushort4(h0, h1, h2, h3);
  ushort4 hiB = make_ushort4(h4, h5, h6, h7);
  ushort4 loA = make_ushort4(f2bf(v0.x - bflo((unsigned)h0)), f2bf(v0.y - bflo((unsigned)h1)),
                             f2bf(v0.z - bflo((unsigned)h2)), f2bf(v0.w - bflo((unsigned)h3)));
  ushort4 loB = make_ushort4(f2bf(v1.x - bflo((unsigned)h4)), f2bf(v1.y - bflo((unsigned)h5)),
                             f2bf(v1.z - bflo((unsigned)h6)), f2bf(v1.w - bflo((unsigned)h7)));
  size_t base = (size_t)node * 1024 + k;
  *(ushort4*)&A2[base]           = hiA;
  *(ushort4*)&A2[base + 4]       = hiB;
  *(ushort4*)&A2[base + 512]     = loA;
  *(ushort4*)&A2[base + 512 + 4] = loB;

  // f64 partial dots for G
  float4 w0a = *(const float4*)&Wg[0 * IN_DIM + k];
  float4 w0b = *(const float4*)&Wg[0 * IN_DIM + k + 4];
  float4 w1a = *(const float4*)&Wg[1 * IN_DIM + k];
  float4 w1b = *(const float4*)&Wg[1 * IN_DIM + k + 4];
  float4 w2a = *(const float4*)&Wg[2 * IN_DIM + k];
  float4 w2b = *(const float4*)&Wg[2 * IN_DIM + k + 4];

  double s0 = 0.0, s1 = 0.0, s2 = 0.0;
  s0 += (double)v0.x * w0a.x; s0 += (double)v0.y * w0a.y;
  s0 += (double)v0.z * w0a.z; s0 += (double)v0.w * w0a.w;
  s0 += (double)v1.x * w0b.x; s0 += (double)v1.y * w0b.y;
  s0 += (double)v1.z * w0b.z; s0 += (double)v1.w * w0b.w;
  s1 += (double)v0.x * w1a.x; s1 += (double)v0.y * w1a.y;
  s1 += (double)v0.z * w1a.z; s1 += (double)v0.w * w1a.w;
  s1 += (double)v1.x * w1b.x; s1 += (double)v1.y * w1b.y;
  s1 += (double)v1.z * w1b.z; s1 += (double)v1.w * w1b.w;
  s2 += (double)v0.x * w2a.x; s2 += (double)v0.y * w2a.y;
  s2 += (double)v0.z * w2a.z; s2 += (double)v0.w * w2a.w;
  s2 += (double)v1.x * w2b.x; s2 += (double)v1.y * w2b.y;
  s2 += (double)v1.z * w2b.z; s2 += (double)v1.w * w2b.w;

  #pragma unroll
  for (int off = 32; off; off >>= 1) {
    s0 += __shfl_down(s0, off);
    s1 += __shfl_down(s1, off);
    s2 += __shfl_down(s2, off);
  }
  if (lane == 0) {
    double sq = s0 * s0 + s1 * s1 + s2 * s2;
    Gx[node] = s0; Gy[node] = s1; Gz[node] = s2; Gsq[node] = sq;
    gpk[node] = make_float4((float)s0, (float)s1, (float)s2, -(float)sq);
  }
}

// ---------------- split W -> B2 = [hi | hi] bf16 (rows: Wq,Wk,Wv) --------
__global__ __launch_bounds__(256) void split_w(const float* __restrict__ Wq,
                                               const float* __restrict__ Wk,
                                               const float* __restrict__ Wv,
                                               ushort* __restrict__ B2) {
  int i = blockIdx.x * 256 + threadIdx.x;
  int n  = i >> 7;
  int kc = (i & 127) << 2;
  const float* W = (n < 512) ? Wq : (n < 1024) ? Wk : Wv;
  int r = n & 511;
  float4 v = *(const float4*)&W[(size_t)r * 512 + kc];
  ushort4 hv = make_ushort4(f2bf(v.x), f2bf(v.y), f2bf(v.z), f2bf(v.w));
  *(ushort4*)&B2[(size_t)n * 1024 + kc]       = hv;
  *(ushort4*)&B2[(size_t)n * 1024 + 512 + kc] = hv;
}

// ---------------- fused Q/K/V bf16 MFMA GEMM (m97 structure) -------------
__global__ __launch_bounds__(256) void gemm_qkv(
    const ushort* __restrict__ A2, const ushort* __restrict__ B2,
    ushort* __restrict__ Q2, ushort* __restrict__ K2, ushort* __restrict__ V2) {
  __shared__ ushort lA[128 * 32];
  __shared__ ushort lB[128 * 32];
  const int tid = threadIdx.x, w = tid >> 6, lane = tid & 63;
  const int id = blockIdx.x;
  const int sw = (id & 7) * 96 + (id >> 3);
  const int bm = sw / 12, bn = sw % 12;
  const int wr = w >> 1, wc = w & 1;

  f32x4 acc[4][4] = {};

  const int   srow = w * 32 + (lane >> 2);
  const int   scol = (lane & 3) * 8;
  const size_t gA0 = (size_t)(bm * 128 + srow) * 1024 + scol;
  const size_t gB0 = (size_t)(bn * 128 + srow) * 1024 + scol;

  for (int k0 = 0; k0 < 1024; k0 += 32) {
    GLOAD_LDS16(&A2[gA0 + k0],             &lA[w * 1024]);
    GLOAD_LDS16(&A2[gA0 + 16 * 1024 + k0], &lA[w * 1024 + 512]);
    GLOAD_LDS16(&B2[gB0 + k0],             &lB[w * 1024]);
    GLOAD_LDS16(&B2[gB0 + 16 * 1024 + k0], &lB[w * 1024 + 512]);
    __syncthreads();

    const int ar = wr * 64 + (lane & 15);
    const int br = wc * 64 + (lane & 15);
    const int kc = (lane >> 4) * 8;
    bf16x8 af[4], bfr[4];
    #pragma unroll
    for (int f = 0; f < 4; ++f) {
      af[f]  = *(const bf16x8*)&lA[(ar + f * 16) * 32 + kc];
      bfr[f] = *(const bf16x8*)&lB[(br + f * 16) * 32 + kc];
    }
    #pragma unroll
    for (int fm = 0; fm < 4; ++fm)
      #pragma unroll
      for (int fn = 0; fn < 4; ++fn)
        acc[fm][fn] = __builtin_amdgcn_mfma_f32_16x16x32_bf16(af[fm], bfr[fn], acc[fm][fn], 0, 0, 0);
    __syncthreads();
  }

  ushort* Cm = (bn < 4) ? Q2 : (bn < 8) ? K2 : V2;
  const int col  = (bn & 3) * 128 + wc * 64 + (lane & 15);
  const int row0 = bm * 128 + wr * 64 + (lane >> 4) * 4;
  #pragma unroll
  for (int fm = 0; fm < 4; ++fm)
    #pragma unroll
    for (int fn = 0; fn < 4; ++fn)
      #pragma unroll
      for (int r = 0; r < 4; ++r)
        Cm[(size_t)(row0 + fm * 16 + r) * 512 + col + fn * 16] = f2bf(acc[fm][fn][r]);
}

// ---------------- knn: 8 queries/block, radix-select, reg-prefetch -------
__global__ __launch_bounds__(256) void knn_kernel(
    const float4* __restrict__ gpk,
    const double* __restrict__ Gx, const double* __restrict__ Gy,
    const double* __restrict__ Gz, const double* __restrict__ Gsq,
    int* __restrict__ knn) {
  const int tid   = threadIdx.x;
  const int w     = tid >> 6;
  const int lane  = tid & 63;
  const int qbase = blockIdx.x * QPB;

  __shared__ float  s_tmax[QPB][256];
  __shared__ int    s_cand[QPB][CAP];
  __shared__ double s_dval[QPB][CAP];
  __shared__ int    s_cnt[QPB];
  __shared__ float  s_T[QPB];

  float q2x[QPB], q2y[QPB], q2z[QPB], tmax[QPB];
  #pragma unroll
  for (int s = 0; s < QPB; ++s) {
    float4 qv = gpk[qbase + s];
    q2x[s] = 2.f * qv.x; q2y[s] = 2.f * qv.y; q2z[s] = 2.f * qv.z;
    tmax[s] = -1e30f;
  }
  if (tid < QPB) s_cnt[tid] = 0;

  // Phase A: branchless max scan, register double-buffer prefetch
  {
    float4 c0 = gpk[tid];
    float4 c1 = gpk[tid + 256];
    for (int i = 0; i < 16; ++i) {
      int nx = ((i + 1) & 15) * 512;
      float4 n0 = gpk[tid + nx];
      float4 n1 = gpk[tid + nx + 256];
      #pragma unroll
      for (int s = 0; s < QPB; ++s) {
        float v0 = fmaf(q2x[s], c0.x, fmaf(q2y[s], c0.y, fmaf(q2z[s], c0.z, c0.w)));
        float v1 = fmaf(q2x[s], c1.x, fmaf(q2y[s], c1.y, fmaf(q2z[s], c1.z, c1.w)));
        tmax[s] = fmaxf(fmaxf(tmax[s], v0), v1);
      }
      c0 = n0; c1 = n1;
    }
  }
  #pragma unroll
  for (int s = 0; s < QPB; ++s) s_tmax[s][tid] = tmax[s];
  __syncthreads();

  // Phase B: exact 16th-of-64 via radix select on monotone float->uint map
  #pragma unroll
  for (int qq = 0; qq < 2; ++qq) {
    int q = w * 2 + qq;
    float v = fmaxf(fmaxf(s_tmax[q][lane], s_tmax[q][lane + 64]),
                    fmaxf(s_tmax[q][lane + 128], s_tmax[q][lane + 192]));
    unsigned b = __float_as_uint(v);
    unsigned u = b ^ ((unsigned)((int)b >> 31) | 0x80000000u);
    unsigned thr = 0;
    for (int bit = 31; bit >= 0; --bit) {
      unsigned cand = thr | (1u << bit);
      unsigned long long m = __ballot(u >= cand);
      if (__popcll(m) >= KN) thr = cand;
    }
    unsigned tb = (thr & 0x80000000u) ? (thr ^ 0x80000000u) : ~thr;
    if (lane == 0) s_T[q] = __uint_as_float(tb);
  }
  __syncthreads();

  // Phase C: rescan (identical FMA chain), collect candidates >= T
  float Ts[QPB];
  #pragma unroll
  for (int s = 0; s < QPB; ++s) Ts[s] = s_T[s];
  {
    float4 c0 = gpk[tid];
    float4 c1 = gpk[tid + 256];
    for (int i = 0; i < 16; ++i) {
      int nx = ((i + 1) & 15) * 512;
      float4 n0 = gpk[tid + nx];
      float4 n1 = gpk[tid + nx + 256];
      int j0 = tid + i * 512, j1 = j0 + 256;
      #pragma unroll
      for (int s = 0; s < QPB; ++s) {
        float v0 = fmaf(q2x[s], c0.x, fmaf(q2y[s], c0.y, fmaf(q2z[s], c0.z, c0.w)));
        float v1 = fmaf(q2x[s], c1.x, fmaf(q2y[s], c1.y, fmaf(q2z[s], c1.z, c1.w)));
        if (v0 >= Ts[s]) { int p = atomicAdd(&s_cnt[s], 1); if (p < CAP) s_cand[s][p] = j0; }
        if (v1 >= Ts[s]) { int p = atomicAdd(&s_cnt[s], 1); if (p < CAP) s_cand[s][p] = j1; }
      }
      c0 = n0; c1 = n1;
    }
  }
  __syncthreads();

  // Phase D: exact f64 scores, rank-by-counting
  const int qA = w * 2, qB = qA + 1;
  const int cntA = min(s_cnt[qA], CAP);
  const int cntB = min(s_cnt[qB], CAP);
  int j0a = -1, j1a = -1, j0b = -1, j1b = -1;
  double v0a = 0, v1a = 0, v0b = 0, v1b = 0;
  {
    int gq = qbase + qA;
    double xi = Gx[gq], yi = Gy[gq], zi = Gz[gq], sqi = Gsq[gq];
    if (lane < cntA) {
      j0a = s_cand[qA][lane];
      v0a = 2.0 * (xi * Gx[j0a] + yi * Gy[j0a] + zi * Gz[j0a]) - sqi - Gsq[j0a];
      s_dval[qA][lane] = v0a;
    }
    if (lane + 64 < cntA) {
      j1a = s_cand[qA][lane + 64];
      v1a = 2.0 * (xi * Gx[j1a] + yi * Gy[j1a] + zi * Gz[j1a]) - sqi - Gsq[j1a];
      s_dval[qA][lane + 64] = v1a;
    }
  }
  {
    int gq = qbase + qB;
    double xi = Gx[gq], yi = Gy[gq], zi = Gz[gq], sqi = Gsq[gq];
    if (lane < cntB) {
      j0b = s_cand[qB][lane];
      v0b = 2.0 * (xi * Gx[j0b] + yi * Gy[j0b] + zi * Gz[j0b]) - sqi - Gsq[j0b];
      s_dval[qB][lane] = v0b;
    }
    if (lane + 64 < cntB) {
      j1b = s_cand[qB][lane + 64];
      v1b = 2.0 * (xi * Gx[j1b] + yi * Gy[j1b] + zi * Gz[j1b]) - sqi - Gsq[j1b];
      s_dval[qB][lane + 64] = v1b;
    }
  }
  __syncthreads();
  {
    int r0 = 0, r1 = 0;
    for (int m = 0; m < cntA; ++m) {
      double dv = s_dval[qA][m]; int di = s_cand[qA][m];
      r0 += (dv > v0a) || (dv == v0a && di < j0a);
      r1 += (dv > v1a) || (dv == v1a && di < j1a);
    }
    int gq = qbase + qA;
    if (j0a >= 0 && r0 < KN) knn[gq * KN + r0] = j0a;
    if (j1a >= 0 && r1 < KN) knn[gq * KN + r1] = j1a;
  }
  {
    int r0 = 0, r1 = 0;
    for (int m = 0; m < cntB; ++m) {
      double dv = s_dval[qB][m]; int di = s_cand[qB][m];
      r0 += (dv > v0b) || (dv == v0b && di < j0b);
      r1 += (dv > v1b) || (dv == v1b && di < j1b);
    }
    int gq = qbase + qB;
    if (j0b >= 0 && r0 < KN) knn[gq * KN + r0] = j0b;
    if (j1b >= 0 && r1 < KN) knn[gq * KN + r1] = j1b;
  }
}

// ---------------- attend: per dst node, 16 neighbors, bf16 Q/K/V ---------
__global__ __launch_bounds__(256) void attend_kernel(
    const ushort* __restrict__ Q2, const ushort* __restrict__ K2, const ushort* __restrict__ V2,
    const double* __restrict__ Gx, const double* __restrict__ Gy, const double* __restrict__ Gz,
    const int* __restrict__ knn, float* __restrict__ out) {
  const int i    = blockIdx.x;
  const int tid  = threadIdx.x;
  const int wv   = tid >> 6;
  const int lane = tid & 63;

  __shared__ int   s_idx[KN];
  __shared__ float s_w[KN];
  __shared__ float s_se[KN];

  if (tid < KN) s_idx[tid] = knn[i * KN + tid];
  __syncthreads();

  uint4 qa = *(const uint4*)&Q2[(size_t)i * 512 + lane * 8];
  float q0 = bflo(qa.x), q1 = bfhi(qa.x), q2 = bflo(qa.y), q3 = bfhi(qa.y);
  float q4 = bflo(qa.z), q5 = bfhi(qa.z), q6 = bflo(qa.w), q7 = bfhi(qa.w);

  float partial[4];
  #pragma unroll
  for (int s = 0; s < 4; ++s) {
    int src = s_idx[wv * 4 + s];
    uint4 ka = *(const uint4*)&K2[(size_t)src * 512 + lane * 8];
    float acc = q0 * bflo(ka.x);
    acc = fmaf(q1, bfhi(ka.x), acc);
    acc = fmaf(q2, bflo(ka.y), acc);
    acc = fmaf(q3, bfhi(ka.y), acc);
    acc = fmaf(q4, bflo(ka.z), acc);
    acc = fmaf(q5, bfhi(ka.z), acc);
    acc = fmaf(q6, bflo(ka.w), acc);
    acc = fmaf(q7, bfhi(ka.w), acc);
    partial[s] = acc;
  }
  #pragma unroll
  for (int s = 0; s < 4; ++s)
    #pragma unroll
    for (int off = 32; off; off >>= 1) partial[s] += __shfl_down(partial[s], off);

  if (lane == 0) {
    const double xi = Gx[i], yi = Gy[i], zi = Gz[i];
    #pragma unroll
    for (int s = 0; s < 4; ++s) {
      int e = wv * 4 + s;
      int src = s_idx[e];
      float sc = partial[s] / 22.627417f;
      sc = fminf(fmaxf(sc, -5.f), 5.f);
      float se = expf(sc);
      double dx = Gx[src] - xi, dy = Gy[src] - yi, dz = Gz[src] - zi;
      double dd = -sqrt(dx * dx + dy * dy + dz * dz + 1e-6);
      double dc = fmin(fmax(dd / 22.627416997969522, -5.0), 5.0);
      float de = (float)exp(dc);
      s_se[e] = se;
      s_w[e]  = se * de;
    }
  }
  __syncthreads();

  float z = 0.f;
  #pragma unroll
  for (int e = 0; e < KN; ++e) z += s_se[e];

  const int d = tid * 2;
  float a0 = 0.f, a1 = 0.f;
  #pragma unroll
  for (int e = 0; e < KN; ++e) {
    unsigned vv = *(const unsigned*)&V2[(size_t)s_idx[e] * 512 + d];
    a0 = fmaf(s_w[e], bflo(vv), a0);
    a1 = fmaf(s_w[e], bfhi(vv), a1);
  }
  float inv = (z > 0.f) ? (1.f / z) : 1.f;
  float2 o = make_float2(a0 * inv, a1 * inv);
  *(float2*)&out[(size_t)i * 512 + d] = o;
}

extern "C" void kernel_launch(void* const* d_in, const int* in_sizes, int n_in,
                              void* d_out, int out_size, void* d_ws, size_t ws_size,
                              hipStream_t stream) {
  const float* h  = (const float*)d_in[0];
  const float* Wq = (const float*)d_in[1];
  const float* Wk = (const float*)d_in[2];
  const float* Wv = (const float*)d_in[3];
  const float* Wg = (const float*)d_in[4];
  float* out = (float*)d_out;

  char* ws = (char*)d_ws;
  ushort* A2 = (ushort*)(ws);
  ushort* B2 = (ushort*)(ws + (16u << 20));
  ushort* Q2 = (ushort*)(ws + (19u << 20));
  ushort* K2 = (ushort*)(ws + (27u << 20));
  ushort* V2 = (ushort*)(ws + (35u << 20));
  float4* gpk = (float4*)(ws + (43u << 20));
  double* Gx  = (double*)(ws + (43u << 20) + (1u << 17));
  double* Gy  = Gx + N_NODES;
  double* Gz  = Gy + N_NODES;
  double* Gsq = Gz + N_NODES;
  int*    knn = (int*)(Gsq + N_NODES);

  hipLaunchKernelGGL(prep_kernel, dim3(N_NODES / 4), dim3(256), 0, stream,
                     h, Wg, A2, Gx, Gy, Gz, Gsq, gpk);
  hipLaunchKernelGGL(split_w, dim3(768), dim3(256), 0, stream, Wq, Wk, Wv, B2);
  hipLaunchKernelGGL(gemm_qkv, dim3(768), dim3(256), 0, stream,
                     A2, B2, Q2, K2, V2);
  hipLaunchKernelGGL(knn_kernel, dim3(N_NODES / QPB), dim3(256), 0, stream,
                     gpk, Gx, Gy, Gz, Gsq, knn);
  hipLaunchKernelGGL(attend_kernel, dim3(N_NODES), dim3(256), 0, stream,
                     Q2, K2, V2, Gx, Gy, Gz, knn, out);
}